// Round 10
// baseline (12.884 us; speedup 1.0000x reference)
//
#include <hip/hip_runtime.h>

// out[b,i,h] = m_i * (1/denom_b) * sum_{j valid} sigmoid(zc[b,i,h] + zy[b,j,h])
// zc = z@Wc^T+bc, zy = z@Wy^T+by.
// sigmoid(a+b) = 1/(1+e^{-a}e^{-b}); E=e^{-zc} (regs), F=e^{-zy} (LDS).
// GRID-HALVING DISCRIMINATOR: 2 graphs per block (grid 256, 1 block/CU).
// In-kernel resources are all ruled out (VALU -35% -> -2%, waves +50% -> 0%,
// LDS -70% -> +4%; four structures pinned at 11.1-11.6us). This tests
// WG-dispatch-ramp (would halve) vs fixed graph-launch overhead (unchanged).
//   - W: coalesced global->LDS staging ONCE, amortized over both graphs.
//   - z: direct from global (half-wave-uniform addresses, L1-resident).
//   - F: transposed F_t[g][h][j], stride 52 -> stage B = 12 ds_read_b128.
// Invalid j: F=1e8 sentinel; fixed 12-quad unrolled loop; 4-way rational
// combine (1 v_rcp per 4 j per row-pair); rows packed in v2f (v_pk_fma_f32).

#define LOG2E 1.4426950408889634f

typedef float v2f __attribute__((ext_vector_type(2)));

constexpr int NV = 48;
constexpr int H  = 32;
constexpr int BLOCK = 768;        // 12 waves; thread = (i0 in 0..23, h in 0..31)
constexpr int WPAD = 36;          // W row stride (floats): 16B-aligned, 4-way
constexpr int FSTRIDE = 52;       // F_t row stride: 16B-aligned b128 rows
constexpr float F_INV = 1.0e8f;   // sentinel for invalid j

__global__ __launch_bounds__(BLOCK, 3)
void OptLinker_attn_kernel(const float* __restrict__ z,
                           const float* __restrict__ Wc,
                           const float* __restrict__ bc,
                           const float* __restrict__ Wy,
                           const float* __restrict__ by,
                           const int*   __restrict__ mask,
                           float* __restrict__ out)
{
    __shared__ float wc_s[H * WPAD];      // 4.5 KB
    __shared__ float wy_s[H * WPAD];      // 4.5 KB
    __shared__ float F_tA[H * FSTRIDE];   // 6.5 KB graph A, transposed [h][j]
    __shared__ float F_tB[H * FSTRIDE];   // 6.5 KB graph B

    const int tid = threadIdx.x;
    const int h   = tid & 31;             // lane's H column
    const int i0  = tid >> 5;             // 0..23; rows i0, i0+24
    const int r0  = i0, r1 = i0 + 24;
    const int lane = tid & 63;
    const int bA  = blockIdx.x * 2;
    const int bB  = bA + 1;

    // ---- mask ballots for both graphs + biases (issue early) ----
    const int mvA = (lane < NV) ? mask[bA * NV + lane] : 0;
    const int mvB = (lane < NV) ? mask[bB * NV + lane] : 0;
    const float bcv = bc[h], byv = by[h];

    // ---- W -> LDS, coalesced, once per block (tid<512) ----
    if (tid < 512) {
        const int q = tid & 255;                    // float4 index within matrix
        const float4 v = (tid < 256) ? ((const float4*)Wc)[q]
                                     : ((const float4*)Wy)[q];
        float* dst = (tid < 256 ? wc_s : wy_s) + (q >> 3) * WPAD + (q & 7) * 4;
        *(float4*)dst = v;                          // 16B-aligned
    }

    const unsigned long long bitsA = __ballot(mvA != 0);
    const unsigned long long bitsB = __ballot(mvB != 0);

    // z row pointers: half-wave-uniform addresses -> broadcast global loads
    const float4* zA0 = (const float4*)(z + (size_t)bA * (NV * H) + r0 * H);
    const float4* zA1 = (const float4*)(z + (size_t)bA * (NV * H) + r1 * H);
    const float4* zB0 = (const float4*)(z + (size_t)bB * (NV * H) + r0 * H);
    const float4* zB1 = (const float4*)(z + (size_t)bB * (NV * H) + r1 * H);

    __syncthreads();   // W staged

    // ---- stage A: 4-row matvec (2 rows x 2 graphs), two-pass over W ----
    auto pass4 = [&](const float* wbase, float bias,
                     float& sA0, float& sA1, float& sB0, float& sB1) {
        float4 w[8];
        #pragma unroll
        for (int q = 0; q < 8; ++q) w[q] = *(const float4*)(wbase + q * 4);
        v2f a0 = {0.f, 0.f}, a1 = {0.f, 0.f}, a2 = {0.f, 0.f}, a3 = {0.f, 0.f};
        #pragma unroll
        for (int q = 0; q < 8; ++q) {
            const v2f wlo = {w[q].x, w[q].y}, whi = {w[q].z, w[q].w};
            const float4 x0 = zA0[q], x1 = zA1[q];
            const float4 x2 = zB0[q], x3 = zB1[q];
            a0 = __builtin_elementwise_fma((v2f){x0.x, x0.y}, wlo, a0);
            a0 = __builtin_elementwise_fma((v2f){x0.z, x0.w}, whi, a0);
            a1 = __builtin_elementwise_fma((v2f){x1.x, x1.y}, wlo, a1);
            a1 = __builtin_elementwise_fma((v2f){x1.z, x1.w}, whi, a1);
            a2 = __builtin_elementwise_fma((v2f){x2.x, x2.y}, wlo, a2);
            a2 = __builtin_elementwise_fma((v2f){x2.z, x2.w}, whi, a2);
            a3 = __builtin_elementwise_fma((v2f){x3.x, x3.y}, wlo, a3);
            a3 = __builtin_elementwise_fma((v2f){x3.z, x3.w}, whi, a3);
        }
        sA0 = a0.x + a0.y + bias;  sA1 = a1.x + a1.y + bias;
        sB0 = a2.x + a2.y + bias;  sB1 = a3.x + a3.y + bias;
    };

    float cA0, cA1, cB0, cB1, yA0, yA1, yB0, yB1;
    pass4(wc_s + h * WPAD, bcv, cA0, cA1, cB0, cB1);   // zc
    pass4(wy_s + h * WPAD, byv, yA0, yA1, yB0, yB1);   // zy

    const float EA0 = __builtin_amdgcn_exp2f(-cA0 * LOG2E);
    const float EA1 = __builtin_amdgcn_exp2f(-cA1 * LOG2E);
    const float EB0 = __builtin_amdgcn_exp2f(-cB0 * LOG2E);
    const float EB1 = __builtin_amdgcn_exp2f(-cB1 * LOG2E);
    F_tA[h * FSTRIDE + r0] = ((bitsA >> r0) & 1ull)
        ? __builtin_amdgcn_exp2f(-yA0 * LOG2E) : F_INV;
    F_tA[h * FSTRIDE + r1] = ((bitsA >> r1) & 1ull)
        ? __builtin_amdgcn_exp2f(-yA1 * LOG2E) : F_INV;
    F_tB[h * FSTRIDE + r0] = ((bitsB >> r0) & 1ull)
        ? __builtin_amdgcn_exp2f(-yB0 * LOG2E) : F_INV;
    F_tB[h * FSTRIDE + r1] = ((bitsB >> r1) & 1ull)
        ? __builtin_amdgcn_exp2f(-yB1 * LOG2E) : F_INV;

    __syncthreads();   // F_t ready

    // ---- stage B: 12 ds_read_b128 per graph, packed rational combine ----
    auto stageB = [&](const float* Ft, float E0, float E1) -> v2f {
        const v2f E2  = {E0, E1};
        const v2f one = {1.f, 1.f};
        v2f acc2 = {0.f, 0.f};
        const float4* frow = (const float4*)(Ft + h * FSTRIDE);
        #pragma unroll
        for (int jq = 0; jq < NV / 4; ++jq) {
            const float4 f = frow[jq];       // 4 F values in one LDS instr
            const v2f t0 = __builtin_elementwise_fma(E2, (v2f){f.x, f.x}, one);
            const v2f t1 = __builtin_elementwise_fma(E2, (v2f){f.y, f.y}, one);
            const v2f t2 = __builtin_elementwise_fma(E2, (v2f){f.z, f.z}, one);
            const v2f t3 = __builtin_elementwise_fma(E2, (v2f){f.w, f.w}, one);
            const v2f p01 = t0 * t1, p23 = t2 * t3;
            const v2f num = __builtin_elementwise_fma(t0 + t1, p23, (t2 + t3) * p01);
            const v2f den = p01 * p23;
            v2f r;
            r.x = __builtin_amdgcn_rcpf(den.x);
            r.y = __builtin_amdgcn_rcpf(den.y);
            acc2 = __builtin_elementwise_fma(num, r, acc2);
        }
        return acc2;
    };

    const v2f accA = stageB(F_tA, EA0, EA1);
    const v2f accB = stageB(F_tB, EB0, EB1);

    // ---- epilogue ----
    const float rdenA = __builtin_amdgcn_rcpf((float)__popcll(bitsA));
    const float rdenB = __builtin_amdgcn_rcpf((float)__popcll(bitsB));
    float* obA = out + (size_t)bA * (NV * H);
    float* obB = out + (size_t)bB * (NV * H);
    obA[r0 * H + h] = ((bitsA >> r0) & 1ull) ? accA.x * rdenA : 0.0f;
    obA[r1 * H + h] = ((bitsA >> r1) & 1ull) ? accA.y * rdenA : 0.0f;
    obB[r0 * H + h] = ((bitsB >> r0) & 1ull) ? accB.x * rdenB : 0.0f;
    obB[r1 * H + h] = ((bitsB >> r1) & 1ull) ? accB.y * rdenB : 0.0f;
}

extern "C" void kernel_launch(void* const* d_in, const int* in_sizes, int n_in,
                              void* d_out, int out_size, void* d_ws, size_t ws_size,
                              hipStream_t stream) {
    const float* z    = (const float*)d_in[0];
    const float* Wc   = (const float*)d_in[1];
    const float* bc   = (const float*)d_in[2];
    const float* Wy   = (const float*)d_in[3];
    const float* by   = (const float*)d_in[4];
    const int*   mask = (const int*)d_in[5];
    float* out = (float*)d_out;

    const int ngraph = in_sizes[0] / (NV * H);   // 512
    OptLinker_attn_kernel<<<ngraph / 2, BLOCK, 0, stream>>>(z, Wc, bc, Wy, by, mask, out);
}

// Round 11
// 11.405 us; speedup vs baseline: 1.1297x; 1.1297x over previous
//
#include <hip/hip_runtime.h>

// out[b,i,h] = m_i * (1/denom_b) * sum_{j valid} sigmoid(zc[b,i,h] + zy[b,j,h])
// zc = z@Wc^T+bc, zy = z@Wy^T+by.
// sigmoid(a+b) = 1/(1+e^{-a}e^{-b}); E=e^{-zc} (regs), F=e^{-zy} (LDS).
// Invalid j: F=1e8 sentinel -> contribution ~1e-8; stage B is a FIXED
// fully-unrolled 48-trip loop. 4-way rational combine -> 1 v_rcp per 4 j.
// Packed f32 (v_pk_fma_f32 via ext_vector_type(2)): stage A packs K,
// stage B packs the thread's two output rows (E2=(E0,E1)).
//
// FINAL STATE (session floor): four structurally different kernels pinned at
// 11.1-11.6us. Eliminated: VALU issue (-35% instr -> -2%), occupancy (+50%
// waves -> 0%), LDS pipe (-70% instr -> +4%), WG dispatch (grid/2 -> hurt).
// Wall = ~8.5us graph-replay/launch overhead + ~2.5-3us kernel busy + ~1us
// HBM (6.2MB). Launch-overhead-bound; not addressable from kernel source.

#define LOG2E 1.4426950408889634f

typedef float v2f __attribute__((ext_vector_type(2)));

constexpr int NV = 48;
constexpr int H  = 32;
constexpr int BLOCK = 768;      // 12 waves; thread = (i0 in 0..23, h in 0..31)
constexpr int WPAD = 36;        // padded W row stride (floats), 16B-aligned rows
constexpr float F_INV = 1.0e8f; // sentinel for invalid j

__global__ __launch_bounds__(BLOCK, 6)
void OptLinker_attn_kernel(const float* __restrict__ z,
                           const float* __restrict__ Wc,
                           const float* __restrict__ bc,
                           const float* __restrict__ Wy,
                           const float* __restrict__ by,
                           const int*   __restrict__ mask,
                           float* __restrict__ out)
{
    __shared__ float z_s[NV * H];       // 6 KB
    __shared__ float F_s[NV * H];       // 6 KB  e^{-zy[j,h]} (or sentinel)
    __shared__ float wc_s[H * WPAD];    // 4.5 KB
    __shared__ float wy_s[H * WPAD];    // 4.5 KB

    const int b   = blockIdx.x;
    const int tid = threadIdx.x;
    const int h   = tid & 31;           // lane's H column
    const int i0  = tid >> 5;           // 0..23; rows i0, i0+24

    // ---- mask + biases prefetch (longest dep chains first) ----
    const int lane = tid & 63;
    const int mv = (lane < NV) ? mask[b * NV + lane] : 0;
    const float bcv = bc[h], byv = by[h];

    // ---- z tile -> LDS (float4, coalesced; 384 float4) ----
    const float4* zb4 = (const float4*)(z + (size_t)b * (NV * H));
    if (tid < (NV * H) / 4) ((float4*)z_s)[tid] = zb4[tid];

    // ---- W -> LDS, coalesced, one float4 per thread (tid<512) ----
    if (tid < 512) {
        const int q = tid & 255;                    // float4 index within matrix
        const float4 v = (tid < 256) ? ((const float4*)Wc)[q]
                                     : ((const float4*)Wy)[q];
        float* dst = (tid < 256 ? wc_s : wy_s) + (q >> 3) * WPAD + (q & 7) * 4;
        *(float4*)dst = v;                          // 16B-aligned
    }

    const unsigned long long bits = __ballot(mv != 0);

    __syncthreads();   // z_s, W LDS ready

    const int r0 = i0, r1 = i0 + 24;
    const float4* zr0 = (const float4*)(z_s + r0 * H);
    const float4* zr1 = (const float4*)(z_s + r1 * H);

    // ---- stage A pass 1 (Wc): packed-K dual-row matvec ----
    float E0, E1;
    {
        float4 w[8];
        const float* wr = wc_s + h * WPAD;
        #pragma unroll
        for (int q = 0; q < 8; ++q) w[q] = *(const float4*)(wr + q * 4);
        v2f a0 = {0.f, 0.f}, a1 = {0.f, 0.f};
        #pragma unroll
        for (int q = 0; q < 8; ++q) {
            const float4 z0 = zr0[q], z1 = zr1[q];  // broadcast ds_read_b128
            const v2f wlo = {w[q].x, w[q].y}, whi = {w[q].z, w[q].w};
            a0 = __builtin_elementwise_fma((v2f){z0.x, z0.y}, wlo, a0);
            a0 = __builtin_elementwise_fma((v2f){z0.z, z0.w}, whi, a0);
            a1 = __builtin_elementwise_fma((v2f){z1.x, z1.y}, wlo, a1);
            a1 = __builtin_elementwise_fma((v2f){z1.z, z1.w}, whi, a1);
        }
        E0 = __builtin_amdgcn_exp2f(-(a0.x + a0.y + bcv) * LOG2E);  // e^{-zc}
        E1 = __builtin_amdgcn_exp2f(-(a1.x + a1.y + bcv) * LOG2E);
    }

    // ---- stage A pass 2 (Wy): wy row replaces wc row ----
    {
        float4 w[8];
        const float* wr = wy_s + h * WPAD;
        #pragma unroll
        for (int q = 0; q < 8; ++q) w[q] = *(const float4*)(wr + q * 4);
        v2f a0 = {0.f, 0.f}, a1 = {0.f, 0.f};
        #pragma unroll
        for (int q = 0; q < 8; ++q) {
            const float4 z0 = zr0[q], z1 = zr1[q];
            const v2f wlo = {w[q].x, w[q].y}, whi = {w[q].z, w[q].w};
            a0 = __builtin_elementwise_fma((v2f){z0.x, z0.y}, wlo, a0);
            a0 = __builtin_elementwise_fma((v2f){z0.z, z0.w}, whi, a0);
            a1 = __builtin_elementwise_fma((v2f){z1.x, z1.y}, wlo, a1);
            a1 = __builtin_elementwise_fma((v2f){z1.z, z1.w}, whi, a1);
        }
        F_s[r0 * H + h] = ((bits >> r0) & 1ull)
            ? __builtin_amdgcn_exp2f(-(a0.x + a0.y + byv) * LOG2E) : F_INV;
        F_s[r1 * H + h] = ((bits >> r1) & 1ull)
            ? __builtin_amdgcn_exp2f(-(a1.x + a1.y + byv) * LOG2E) : F_INV;
    }

    __syncthreads();   // F_s ready

    // ---- stage B: fixed 48-trip loop, rows packed as v2f lanes ----
    const v2f E2  = {E0, E1};
    const v2f one = {1.f, 1.f};
    v2f acc2 = {0.f, 0.f};
    #pragma unroll
    for (int j = 0; j < NV; j += 4) {
        const float f0 = F_s[(j + 0) * H + h];   // conflict-free broadcast
        const float f1 = F_s[(j + 1) * H + h];
        const float f2 = F_s[(j + 2) * H + h];
        const float f3 = F_s[(j + 3) * H + h];
        const v2f t0 = __builtin_elementwise_fma(E2, (v2f){f0, f0}, one);
        const v2f t1 = __builtin_elementwise_fma(E2, (v2f){f1, f1}, one);
        const v2f t2 = __builtin_elementwise_fma(E2, (v2f){f2, f2}, one);
        const v2f t3 = __builtin_elementwise_fma(E2, (v2f){f3, f3}, one);
        const v2f p01 = t0 * t1, p23 = t2 * t3;
        const v2f num = __builtin_elementwise_fma(t0 + t1, p23, (t2 + t3) * p01);
        const v2f den = p01 * p23;
        v2f r;
        r.x = __builtin_amdgcn_rcpf(den.x);
        r.y = __builtin_amdgcn_rcpf(den.y);
        acc2 = __builtin_elementwise_fma(num, r, acc2);
    }

    // ---- epilogue ----
    const int nvalid = __popcll(bits);
    const float rden = __builtin_amdgcn_rcpf((float)nvalid);
    float* ob = out + (size_t)b * (NV * H);
    ob[r0 * H + h] = ((bits >> r0) & 1ull) ? acc2.x * rden : 0.0f;
    ob[r1 * H + h] = ((bits >> r1) & 1ull) ? acc2.y * rden : 0.0f;
}

extern "C" void kernel_launch(void* const* d_in, const int* in_sizes, int n_in,
                              void* d_out, int out_size, void* d_ws, size_t ws_size,
                              hipStream_t stream) {
    const float* z    = (const float*)d_in[0];
    const float* Wc   = (const float*)d_in[1];
    const float* bc   = (const float*)d_in[2];
    const float* Wy   = (const float*)d_in[3];
    const float* by   = (const float*)d_in[4];
    const int*   mask = (const int*)d_in[5];
    float* out = (float*)d_out;

    const int ngraph = in_sizes[0] / (NV * H);   // 512
    OptLinker_attn_kernel<<<ngraph, BLOCK, 0, stream>>>(z, Wc, bc, Wy, by, mask, out);
}